// Round 3
// baseline (199.633 us; speedup 1.0000x reference)
//
#include <hip/hip_runtime.h>

#define BB 1024
#define DD 512
#define BTILE 64     // batch rows per block (8 groups x 8 rows)
#define JTILE 256    // j columns per block (32 lanes x (4 + 4 split) cols)
#define ICH 16       // i depth per block
#define NIC (DD / ICH)              // 32 i-chunks
#define NJC (DD / JTILE)            // 2 j-chunks
#define NTP (NJC * NIC)             // 64 t-partial rows per b
#define NNP NIC                     // 32 norm-partial rows per b
#define NROWS (NTP + NNP)           // 96 partial rows (384 KB, L2-resident)
#define XDLD (BTILE + 4)            // 68: 16B align kept, store conflicts 2-way (free)

// out[b] = ||x_dot[b]||^2 + t[b]^2,  t[b] = sum_{i,j} x_dot[b,i] W[i,j] x[b,j]
//
// Round-2 post-mortem: k1+k2 = 14.8 us (total - 40.5 fill - 13.3 fixed graph
// overhead). k1 was LDS-ISSUE-bound: 1536 ds_read_b128/CU (2/3 of them x_dot
// broadcasts) vs 3.4 us of FMA. This version: 8x8 register tile -> 64 FMAs
// per 4 reads, 1024 reads/CU, all conflict-free:
//   - each lane owns SPLIT columns {j0+4tj..+3, j0+128+4tj..+3} so both W
//     reads are 16B-stride (the naive 8-contiguous-col read is a 4-way
//     half-banks conflict). Correct because the block sums over all its j.
//   - no x prefetch (VGPR budget: acc 64 + temps ~110 <= 128 -> 4 waves/SIMD);
//     epilogue x loads hit L2 (x re-read 32x across ic-blocks -> hot).
// k2 spread over 8 blocks. No fences/atomics (round-1 lesson).
__global__ __launch_bounds__(256, 4) void stm_main_kernel(
    const float* __restrict__ x, const float* __restrict__ xdot,
    const float* __restrict__ W, float* __restrict__ ws) {
  __shared__ float xd_t[ICH][XDLD];   // 4.25 KB transposed x_dot chunk [i][b]
  __shared__ float w_s[ICH][JTILE];   // 16 KB W tile

  const int tid = threadIdx.x;
  const int b0 = blockIdx.x * BTILE;
  const int j0 = blockIdx.y * JTILE;
  const int i0 = blockIdx.z * ICH;
  const int tb = tid >> 5;   // 0..7  -> rows b0 + 8*tb .. +7
  const int tj = tid & 31;   // 0..31 -> cols {j0+4tj..+3} and {j0+128+4tj..+3}

  // Stage x_dot chunk transposed: 64 rows x 16 cols = 256 float4, 1/thread.
  // 4 consecutive lanes per row (64B segments). Squares for the norm.
  float nrm;
  {
    const int row = tid >> 2;            // 0..63
    const int q = tid & 3;               // 0..3
    const float4 v = ((const float4*)(xdot + (size_t)(b0 + row) * DD + i0))[q];
    nrm = v.x * v.x + v.y * v.y + v.z * v.z + v.w * v.w;
    const int c = q * 4;
    xd_t[c + 0][row] = v.x; xd_t[c + 1][row] = v.y;
    xd_t[c + 2][row] = v.z; xd_t[c + 3][row] = v.w;
  }
  // Stage W tile: 16 rows x 256 cols = 1024 float4, 4/thread, coalesced.
  {
#pragma unroll
    for (int v = 0; v < 4; ++v) {
      const int f4 = tid + v * 256;
      const int ii = f4 >> 6, jj4 = f4 & 63;
      *((float4*)&w_s[ii][jj4 * 4]) =
          ((const float4*)(W + (size_t)(i0 + ii) * DD + j0))[jj4];
    }
  }

  // Norm partials: a row's 4 stagers are consecutive lanes -> 2 xor folds.
  if (blockIdx.y == 0) {
    nrm += __shfl_xor(nrm, 1);
    nrm += __shfl_xor(nrm, 2);
    if ((tid & 3) == 0)
      ws[(size_t)(NTP + blockIdx.z) * BB + b0 + (tid >> 2)] = nrm;
  }

  __syncthreads();

  // acc[r][c]: c=0..3 -> cols j0+4tj+c ; c=4..7 -> cols j0+128+4tj+(c-4).
  float acc[8][8] = {};
#pragma unroll
  for (int i = 0; i < ICH; ++i) {
    const float4 xa = *(const float4*)&xd_t[i][tb * 8];        // broadcast
    const float4 xb = *(const float4*)&xd_t[i][tb * 8 + 4];    // broadcast
    const float4 wa = *(const float4*)&w_s[i][tj * 4];         // 16B stride, CF
    const float4 wb = *(const float4*)&w_s[i][128 + tj * 4];   // 16B stride, CF
    const float xr[8] = {xa.x, xa.y, xa.z, xa.w, xb.x, xb.y, xb.z, xb.w};
    const float wc[8] = {wa.x, wa.y, wa.z, wa.w, wb.x, wb.y, wb.z, wb.w};
#pragma unroll
    for (int r = 0; r < 8; ++r) {
#pragma unroll
      for (int c = 0; c < 8; ++c) acc[r][c] += xr[r] * wc[c];
    }
  }

  // Epilogue: contract with x (L2-hot), reduce over the 32 tj lanes.
  float tp[8] = {0.f, 0.f, 0.f, 0.f, 0.f, 0.f, 0.f, 0.f};
#pragma unroll
  for (int h = 0; h < 2; ++h) {
    const int jc = j0 + h * 128 + tj * 4;
#pragma unroll
    for (int r = 0; r < 8; ++r) {
      const float4 xv = *(const float4*)(x + (size_t)(b0 + tb * 8 + r) * DD + jc);
      tp[r] += acc[r][h * 4 + 0] * xv.x + acc[r][h * 4 + 1] * xv.y +
               acc[r][h * 4 + 2] * xv.z + acc[r][h * 4 + 3] * xv.w;
    }
  }
#pragma unroll
  for (int off = 16; off >= 1; off >>= 1) {
#pragma unroll
    for (int r = 0; r < 8; ++r) tp[r] += __shfl_xor(tp[r], off);
  }
  if (tj == 0) {
    const int p = blockIdx.y * NIC + blockIdx.z;   // 0..63
    float* dst = ws + (size_t)p * BB + b0 + tb * 8;
    *(float4*)(dst + 0) = make_float4(tp[0], tp[1], tp[2], tp[3]);
    *(float4*)(dst + 4) = make_float4(tp[4], tp[5], tp[6], tp[7]);
  }
}

// k2: one thread per b over 96 L2-resident partial rows, coalesced across b.
// 8 blocks (vs 4) to spread across CUs. Fixed order -> deterministic.
__global__ __launch_bounds__(128) void stm_final_kernel(
    const float* __restrict__ ws, float* __restrict__ out) {
  const int b = blockIdx.x * 128 + threadIdx.x;
  float t = 0.f, n = 0.f;
#pragma unroll
  for (int p = 0; p < NTP; ++p) t += ws[(size_t)p * BB + b];
#pragma unroll
  for (int p = 0; p < NNP; ++p) n += ws[(size_t)(NTP + p) * BB + b];
  out[b] = n + t * t;
}

extern "C" void kernel_launch(void* const* d_in, const int* in_sizes, int n_in,
                              void* d_out, int out_size, void* d_ws, size_t ws_size,
                              hipStream_t stream) {
  const float* x    = (const float*)d_in[0];
  const float* xdot = (const float*)d_in[1];
  const float* W    = (const float*)d_in[2];
  float* ws = (float*)d_ws;   // 96 * 1024 floats = 384 KB of partials
  float* out = (float*)d_out;

  dim3 g1(BB / BTILE, DD / JTILE, NIC);  // (16, 2, 32) = 1024 blocks, 4/CU
  stm_main_kernel<<<g1, 256, 0, stream>>>(x, xdot, W, ws);
  stm_final_kernel<<<BB / 128, 128, 0, stream>>>(ws, out);
}

// Round 4
// 182.669 us; speedup vs baseline: 1.0929x; 1.0929x over previous
//
#include <hip/hip_runtime.h>

#define BB 1024
#define DD 512
#define BTILE 64     // batch rows per block (8 groups x 8 rows)
#define JTILE 256    // j columns per block (32 lanes x (4 + 4 split) cols)
#define ICH 16       // i depth per block
#define NIC (DD / ICH)              // 32 i-chunks
#define NJC (DD / JTILE)            // 2 j-chunks
#define NTP (NJC * NIC)             // 64 t-partial rows per b
#define NNP NIC                     // 32 norm-partial rows per b
#define NROWS (NTP + NNP)           // 96 partial rows (384 KB, L2-resident)
#define XDLD (BTILE + 4)            // 68: 16B align kept

// out[b] = ||x_dot[b]||^2 + t[b]^2,  t[b] = sum_{i,j} x_dot[b,i] W[i,j] x[b,j]
//
// Round-3 post-mortem: acc[8][8] + staging arrays were demoted to scratch
// (VGPR_Count=64, 282MB scratch writes, 159us). The 8x8 tile itself was
// never actually measured. This version keeps the 8x8 geometry (64 FMAs per
// 4 ds_read_b128 -> LDS pipe ~3.3us/CU, below the 3.4us FMA floor) but uses
// SIXTEEN EXPLICITLY NAMED float4 accumulators via macro expansion - no
// runtime-indexable array exists, so the allocator cannot demote them.
// ~100 VGPR < 128 cap at (256,4). Split columns {4tj, 128+4tj} keep both W
// reads 16B-stride (2-way bank aliasing = free per m136).
__global__ __launch_bounds__(256, 4) void stm_main_kernel(
    const float* __restrict__ x, const float* __restrict__ xdot,
    const float* __restrict__ W, float* __restrict__ ws) {
  __shared__ float xd_t[ICH][XDLD];   // 4.25 KB transposed x_dot chunk [i][b]
  __shared__ float w_s[ICH][JTILE];   // 16 KB W tile

  const int tid = threadIdx.x;
  const int b0 = blockIdx.x * BTILE;
  const int j0 = blockIdx.y * JTILE;
  const int i0 = blockIdx.z * ICH;
  const int tb = tid >> 5;   // 0..7  -> rows b0 + 8*tb .. +7
  const int tj = tid & 31;   // 0..31 -> cols {j0+4tj..+3} and {j0+128+4tj..+3}

  // Stage x_dot chunk transposed: 64 rows x 16 cols = 256 float4, 1/thread.
  float nrm;
  {
    const int row = tid >> 2;            // 0..63
    const int q = tid & 3;               // 0..3
    const float4 v = ((const float4*)(xdot + (size_t)(b0 + row) * DD + i0))[q];
    nrm = v.x * v.x + v.y * v.y + v.z * v.z + v.w * v.w;
    const int c = q * 4;
    xd_t[c + 0][row] = v.x; xd_t[c + 1][row] = v.y;
    xd_t[c + 2][row] = v.z; xd_t[c + 3][row] = v.w;
  }
  // Stage W tile: 16 rows x 256 cols = 1024 float4, 4/thread, coalesced
  // (each 64-lane wave covers one full 1KB row).
  {
#pragma unroll
    for (int v = 0; v < 4; ++v) {
      const int f4 = tid + v * 256;
      const int ii = f4 >> 6, jj4 = f4 & 63;
      *((float4*)&w_s[ii][jj4 * 4]) =
          ((const float4*)(W + (size_t)(i0 + ii) * DD + j0))[jj4];
    }
  }

  // Norm partials: a row's 4 stagers are consecutive lanes -> 2 xor folds.
  if (blockIdx.y == 0) {
    nrm += __shfl_xor(nrm, 1);
    nrm += __shfl_xor(nrm, 2);
    if ((tid & 3) == 0)
      ws[(size_t)(NTP + blockIdx.z) * BB + b0 + (tid >> 2)] = nrm;
  }

  __syncthreads();

  // 16 named float4 accumulators: aRl = cols j0+4tj..+3, aRh = j0+128+4tj..+3
  float4 a0l = make_float4(0.f, 0.f, 0.f, 0.f), a0h = a0l;
  float4 a1l = a0l, a1h = a0l, a2l = a0l, a2h = a0l, a3l = a0l, a3h = a0l;
  float4 a4l = a0l, a4h = a0l, a5l = a0l, a5h = a0l, a6l = a0l, a6h = a0l;
  float4 a7l = a0l, a7h = a0l;

#define UPD(AL, AH, S)                                          \
  AL.x += (S) * wa.x; AL.y += (S) * wa.y;                       \
  AL.z += (S) * wa.z; AL.w += (S) * wa.w;                       \
  AH.x += (S) * wb.x; AH.y += (S) * wb.y;                       \
  AH.z += (S) * wb.z; AH.w += (S) * wb.w;

#pragma unroll
  for (int i = 0; i < ICH; ++i) {
    const float4 xa = *(const float4*)&xd_t[i][tb * 8];        // broadcast
    const float4 xb = *(const float4*)&xd_t[i][tb * 8 + 4];    // broadcast
    const float4 wa = *(const float4*)&w_s[i][tj * 4];         // CF, 2-way free
    const float4 wb = *(const float4*)&w_s[i][128 + tj * 4];   // CF, 2-way free
    UPD(a0l, a0h, xa.x) UPD(a1l, a1h, xa.y)
    UPD(a2l, a2h, xa.z) UPD(a3l, a3h, xa.w)
    UPD(a4l, a4h, xb.x) UPD(a5l, a5h, xb.y)
    UPD(a6l, a6h, xb.z) UPD(a7l, a7h, xb.w)
  }
#undef UPD

  // Epilogue: contract with x (L2-hot: 2MB x re-read by 32 ic-blocks).
  float tp[8];
#define EPI(R, AL, AH)                                                        \
  {                                                                           \
    const float* xr = x + (size_t)(b0 + tb * 8 + R) * DD + j0;                \
    const float4 xva = *(const float4*)(xr + tj * 4);                         \
    const float4 xvb = *(const float4*)(xr + 128 + tj * 4);                   \
    tp[R] = AL.x * xva.x + AL.y * xva.y + AL.z * xva.z + AL.w * xva.w +       \
            AH.x * xvb.x + AH.y * xvb.y + AH.z * xvb.z + AH.w * xvb.w;        \
  }
  EPI(0, a0l, a0h) EPI(1, a1l, a1h) EPI(2, a2l, a2h) EPI(3, a3l, a3h)
  EPI(4, a4l, a4h) EPI(5, a5l, a5h) EPI(6, a6l, a6h) EPI(7, a7l, a7h)
#undef EPI

#pragma unroll
  for (int off = 16; off >= 1; off >>= 1) {
#pragma unroll
    for (int r = 0; r < 8; ++r) tp[r] += __shfl_xor(tp[r], off);
  }
  if (tj == 0) {
    const int p = blockIdx.y * NIC + blockIdx.z;   // 0..63
    float* dst = ws + (size_t)p * BB + b0 + tb * 8;
    *(float4*)(dst + 0) = make_float4(tp[0], tp[1], tp[2], tp[3]);
    *(float4*)(dst + 4) = make_float4(tp[4], tp[5], tp[6], tp[7]);
  }
}

// k2: 4 threads per b (16 blocks x 256 thr), 24 loads/thread over the
// 96 L2-resident partial rows, 2 shfl folds. Fixed order -> deterministic.
__global__ __launch_bounds__(256) void stm_final_kernel(
    const float* __restrict__ ws, float* __restrict__ out) {
  const int tid = threadIdx.x;
  const int b = blockIdx.x * 64 + (tid >> 2);
  const int part = tid & 3;
  float t = 0.f, n = 0.f;
#pragma unroll
  for (int k = 0; k < 16; ++k) t += ws[(size_t)(part * 16 + k) * BB + b];
#pragma unroll
  for (int k = 0; k < 8; ++k) n += ws[(size_t)(NTP + part * 8 + k) * BB + b];
  t += __shfl_xor(t, 1); t += __shfl_xor(t, 2);
  n += __shfl_xor(n, 1); n += __shfl_xor(n, 2);
  if (part == 0) out[b] = n + t * t;
}

extern "C" void kernel_launch(void* const* d_in, const int* in_sizes, int n_in,
                              void* d_out, int out_size, void* d_ws, size_t ws_size,
                              hipStream_t stream) {
  const float* x    = (const float*)d_in[0];
  const float* xdot = (const float*)d_in[1];
  const float* W    = (const float*)d_in[2];
  float* ws = (float*)d_ws;   // 96 * 1024 floats = 384 KB of partials
  float* out = (float*)d_out;

  dim3 g1(BB / BTILE, DD / JTILE, NIC);  // (16, 2, 32) = 1024 blocks, 4/CU
  stm_main_kernel<<<g1, 256, 0, stream>>>(x, xdot, W, ws);
  stm_final_kernel<<<16, 256, 0, stream>>>(ws, out);
}

// Round 5
// 68.624 us; speedup vs baseline: 2.9091x; 2.6619x over previous
//
#include <hip/hip_runtime.h>

#define BB 1024
#define DD 512
#define BTILE 64     // batch rows per block (8 groups x 8 rows)
#define JTILE 256    // j columns per block (32 lanes x (4 + 4 split) cols)
#define ICH 16       // i depth per block
#define NIC (DD / ICH)              // 32 i-chunks
#define NJC (DD / JTILE)            // 2 j-chunks
#define NTP (NJC * NIC)             // 64 t-partial rows per b
#define NNP NIC                     // 32 norm-partial rows per b
#define NROWS (NTP + NNP)           // 96 partial rows (384 KB, L2-resident)
#define XDLD (BTILE + 4)            // 68: 16B align kept

// out[b] = ||x_dot[b]||^2 + t[b]^2,  t[b] = sum_{i,j} x_dot[b,i] W[i,j] x[b,j]
//
// Round-4 post-mortem: the 8x8 tile spilled AGAIN under launch_bounds(256,4)
// (VGPR=64, 255MB scratch). Mechanism: the 128-VGPR cap + full unroll of the
// ICH=16 loop (scheduler hoists up to 64 ds_read results) -> estimated
// pressure > cap -> RA spill cascade. Fix both sides:
//   - __launch_bounds__(256, 2): cap 256 VGPR. Actual demand ~110-130 still
//     gives floor(512/VGPR) = 4 waves/SIMD -> 4 blocks/CU, same occupancy.
//   - #pragma unroll 4 on the i-loop: hoist window <= 16 ds_reads.
// Tile stays 8x8 (64 FMAs per 4 ds_read_b128): LDS pipe ~4us/CU, below the
// 3.4us FMA floor for the first time. Named float4 accumulators (no runtime-
// indexed arrays). Split cols {4tj, 128+4tj}: both W reads 16B-stride.
__global__ __launch_bounds__(256, 2) void stm_main_kernel(
    const float* __restrict__ x, const float* __restrict__ xdot,
    const float* __restrict__ W, float* __restrict__ ws) {
  __shared__ float xd_t[ICH][XDLD];   // 4.25 KB transposed x_dot chunk [i][b]
  __shared__ float w_s[ICH][JTILE];   // 16 KB W tile

  const int tid = threadIdx.x;
  const int b0 = blockIdx.x * BTILE;
  const int j0 = blockIdx.y * JTILE;
  const int i0 = blockIdx.z * ICH;
  const int tb = tid >> 5;   // 0..7  -> rows b0 + 8*tb .. +7
  const int tj = tid & 31;   // 0..31 -> cols {j0+4tj..+3} and {j0+128+4tj..+3}

  // Stage x_dot chunk transposed: 64 rows x 16 cols = 256 float4, 1/thread.
  float nrm;
  {
    const int row = tid >> 2;            // 0..63
    const int q = tid & 3;               // 0..3
    const float4 v = ((const float4*)(xdot + (size_t)(b0 + row) * DD + i0))[q];
    nrm = v.x * v.x + v.y * v.y + v.z * v.z + v.w * v.w;
    const int c = q * 4;
    xd_t[c + 0][row] = v.x; xd_t[c + 1][row] = v.y;
    xd_t[c + 2][row] = v.z; xd_t[c + 3][row] = v.w;
  }
  // Stage W tile: 16 rows x 256 cols = 1024 float4, 4/thread, coalesced
  // (each 64-lane wave covers one full 1KB row).
  {
#pragma unroll
    for (int v = 0; v < 4; ++v) {
      const int f4 = tid + v * 256;
      const int ii = f4 >> 6, jj4 = f4 & 63;
      *((float4*)&w_s[ii][jj4 * 4]) =
          ((const float4*)(W + (size_t)(i0 + ii) * DD + j0))[jj4];
    }
  }

  // Norm partials: a row's 4 stagers are consecutive lanes -> 2 xor folds.
  if (blockIdx.y == 0) {
    nrm += __shfl_xor(nrm, 1);
    nrm += __shfl_xor(nrm, 2);
    if ((tid & 3) == 0)
      ws[(size_t)(NTP + blockIdx.z) * BB + b0 + (tid >> 2)] = nrm;
  }

  __syncthreads();

  // 16 named float4 accumulators: aRl = cols j0+4tj..+3, aRh = j0+128+4tj..+3
  float4 a0l = make_float4(0.f, 0.f, 0.f, 0.f), a0h = a0l;
  float4 a1l = a0l, a1h = a0l, a2l = a0l, a2h = a0l, a3l = a0l, a3h = a0l;
  float4 a4l = a0l, a4h = a0l, a5l = a0l, a5h = a0l, a6l = a0l, a6h = a0l;
  float4 a7l = a0l, a7h = a0l;

#define UPD(AL, AH, S)                                          \
  AL.x += (S) * wa.x; AL.y += (S) * wa.y;                       \
  AL.z += (S) * wa.z; AL.w += (S) * wa.w;                       \
  AH.x += (S) * wb.x; AH.y += (S) * wb.y;                       \
  AH.z += (S) * wb.z; AH.w += (S) * wb.w;

#pragma unroll 4
  for (int i = 0; i < ICH; ++i) {
    const float4 xa = *(const float4*)&xd_t[i][tb * 8];        // broadcast
    const float4 xb = *(const float4*)&xd_t[i][tb * 8 + 4];    // broadcast
    const float4 wa = *(const float4*)&w_s[i][tj * 4];         // 16B stride
    const float4 wb = *(const float4*)&w_s[i][128 + tj * 4];   // 16B stride
    UPD(a0l, a0h, xa.x) UPD(a1l, a1h, xa.y)
    UPD(a2l, a2h, xa.z) UPD(a3l, a3h, xa.w)
    UPD(a4l, a4h, xb.x) UPD(a5l, a5h, xb.y)
    UPD(a6l, a6h, xb.z) UPD(a7l, a7h, xb.w)
  }
#undef UPD

  // Epilogue: contract with x (L2-hot: 2MB x re-read by 32 ic-blocks).
  float tp[8];
#define EPI(R, AL, AH)                                                        \
  {                                                                           \
    const float* xr = x + (size_t)(b0 + tb * 8 + R) * DD + j0;                \
    const float4 xva = *(const float4*)(xr + tj * 4);                         \
    const float4 xvb = *(const float4*)(xr + 128 + tj * 4);                   \
    tp[R] = AL.x * xva.x + AL.y * xva.y + AL.z * xva.z + AL.w * xva.w +       \
            AH.x * xvb.x + AH.y * xvb.y + AH.z * xvb.z + AH.w * xvb.w;        \
  }
  EPI(0, a0l, a0h) EPI(1, a1l, a1h) EPI(2, a2l, a2h) EPI(3, a3l, a3h)
  EPI(4, a4l, a4h) EPI(5, a5l, a5h) EPI(6, a6l, a6h) EPI(7, a7l, a7h)
#undef EPI

#pragma unroll
  for (int off = 16; off >= 1; off >>= 1) {
#pragma unroll
    for (int r = 0; r < 8; ++r) tp[r] += __shfl_xor(tp[r], off);
  }
  if (tj == 0) {
    const int p = blockIdx.y * NIC + blockIdx.z;   // 0..63
    float* dst = ws + (size_t)p * BB + b0 + tb * 8;
    *(float4*)(dst + 0) = make_float4(tp[0], tp[1], tp[2], tp[3]);
    *(float4*)(dst + 4) = make_float4(tp[4], tp[5], tp[6], tp[7]);
  }
}

// k2: 4 threads per b (16 blocks x 256 thr), 24 loads/thread over the
// 96 L2-resident partial rows, 2 shfl folds. Fixed order -> deterministic.
__global__ __launch_bounds__(256) void stm_final_kernel(
    const float* __restrict__ ws, float* __restrict__ out) {
  const int tid = threadIdx.x;
  const int b = blockIdx.x * 64 + (tid >> 2);
  const int part = tid & 3;
  float t = 0.f, n = 0.f;
#pragma unroll
  for (int k = 0; k < 16; ++k) t += ws[(size_t)(part * 16 + k) * BB + b];
#pragma unroll
  for (int k = 0; k < 8; ++k) n += ws[(size_t)(NTP + part * 8 + k) * BB + b];
  t += __shfl_xor(t, 1); t += __shfl_xor(t, 2);
  n += __shfl_xor(n, 1); n += __shfl_xor(n, 2);
  if (part == 0) out[b] = n + t * t;
}

extern "C" void kernel_launch(void* const* d_in, const int* in_sizes, int n_in,
                              void* d_out, int out_size, void* d_ws, size_t ws_size,
                              hipStream_t stream) {
  const float* x    = (const float*)d_in[0];
  const float* xdot = (const float*)d_in[1];
  const float* W    = (const float*)d_in[2];
  float* ws = (float*)d_ws;   // 96 * 1024 floats = 384 KB of partials
  float* out = (float*)d_out;

  dim3 g1(BB / BTILE, DD / JTILE, NIC);  // (16, 2, 32) = 1024 blocks, 4/CU
  stm_main_kernel<<<g1, 256, 0, stream>>>(x, xdot, W, ws);
  stm_final_kernel<<<16, 256, 0, stream>>>(ws, out);
}